// Round 4
// baseline (8613.000 us; speedup 1.0000x reference)
//
#include <hip/hip_runtime.h>

// ---------------------------------------------------------------------------
// TLSTM (time-aware LSTM): B=256, S=512, D=H=512, FC=64, O=2
//
// Round-4 design: fully XCD-local communication (L2-only, zero IC ops).
//   * persistent kernel, 256 WGs = 16 rowg x 16 colg; all WGs of a rowg land
//     on one XCD (bid&7 == rowg&7) -> h/c exchange + barrier via shared L2.
//   * CDNA L1 is read-only: plain stores go straight to L2 (write-back, no
//     HBM write-through). Peer reads use sc0 loads (L1 bypass, L2 serve).
//   * barrier: 16-slot epoch flag array per rowg; each WG plain-stores its
//     epoch, wave0 lanes 0-15 poll all slots in parallel (ballot). No atomic
//     RMW -> no fabric serialization, no Infinity-Cache round trips.
//   * x_t and tim prefetched one step ahead into registers (HBM latency off
//     the serial chain).
//   * weights f16 B^T fragments register/AGPR-resident (unchanged).
//
// NOTE (round-8): this is a BYTE-IDENTICAL resubmission of the round-0
// kernel that measured 8602 µs on this harness. Rounds 5-7 all failed with
// an infra-shaped ExceptionGroup (no JSON fields), including round-7 whose
// only delta was an innocent single-thread code motion. This run bisects
// harness-vs-kernel: if it fails, the harness is broken; if it passes, the
// baseline is re-anchored and the next round makes exactly one audited edit.
// ---------------------------------------------------------------------------

typedef _Float16 f16;
typedef _Float16 f16x8 __attribute__((ext_vector_type(8)));
typedef float f32x4 __attribute__((ext_vector_type(4)));
typedef unsigned u32x4 __attribute__((ext_vector_type(4)));

#define B_ 256
#define S_ 512
#define D_ 512
#define H_ 512

// workspace layout (bytes)
#define WS_WTG  0u          // f16 [2048][1024] gate weights^T (W|U stacked on K)
#define WS_WTD  4194304u    // f16 [512][512]   decomp weights^T
#define WS_H16  4718592u    // f16 [2][256][512] h double buffer
#define WS_C16  5242880u    // f16 [2][256][512] c double buffer
#define WS_HF32 5767168u    // f32 [256][512]   h last (for head)
#define WS_FLG  6291456u    // u32 [16][16] epoch flags (rowg-major, 64B/rowg)
#define WS_END  6292480u

__device__ __forceinline__ float fast_sigmoid(float x) {
  return 1.0f / (1.0f + __expf(-x));
}
__device__ __forceinline__ float fast_tanh(float x) {
  x = fminf(15.0f, fmaxf(-15.0f, x));
  float e = __expf(2.0f * x);
  return (e - 1.0f) / (e + 1.0f);
}
__device__ __forceinline__ unsigned pack_f16x2(float a, float b) {
  union { f16 h[2]; unsigned u; } p;
  p.h[0] = (f16)a; p.h[1] = (f16)b;
  return p.u;
}

// ---------------------------------------------------------------------------
// Pack weights: WT_g[n][k] (n = gate*512+col; k<512 -> W[k][col], k>=512 ->
// U[k-512][col]), WT_d[n][k] = W_decomp[k][n].
// ---------------------------------------------------------------------------
__global__ void pack_weights(const float* __restrict__ Wi, const float* __restrict__ Ui,
                             const float* __restrict__ Wf, const float* __restrict__ Uf,
                             const float* __restrict__ Wog, const float* __restrict__ Uog,
                             const float* __restrict__ Wc, const float* __restrict__ Uc,
                             const float* __restrict__ Wd,
                             f16* __restrict__ wtg, f16* __restrict__ wtd)
{
  const int idx = blockIdx.x * 256 + threadIdx.x;
  if (idx < 2048 * 1024) {
    const int n = idx >> 10, k = idx & 1023;
    const int g = n >> 9, j = n & 511;
    const float* W[8] = {Wi, Ui, Wf, Uf, Wog, Uog, Wc, Uc};
    const float* src = W[(g << 1) + (k >> 9)];
    wtg[idx] = (f16)src[(size_t)(k & 511) * 512 + j];
  } else {
    const int i2 = idx - 2048 * 1024;
    const int n = i2 >> 9, k = i2 & 511;
    wtd[i2] = (f16)Wd[(size_t)k * 512 + n];
  }
}

// ---------------------------------------------------------------------------
// Main persistent kernel.
// ---------------------------------------------------------------------------
__global__ void __launch_bounds__(256, 1)
tlstm_main(const float* __restrict__ x, const float* __restrict__ tim,
           const float* __restrict__ bi, const float* __restrict__ bf,
           const float* __restrict__ bog, const float* __restrict__ bc,
           const float* __restrict__ bdec,
           const f16* __restrict__ wtg, const f16* __restrict__ wtd,
           f16* __restrict__ h16, f16* __restrict__ c16,
           float* __restrict__ hf32, unsigned* __restrict__ flg_base)
{
  __shared__ __align__(16) f16 Ag[16][1032];   // [row][k]: k<512 x_t, k>=512 h_prev
  __shared__ __align__(16) f16 Ad[16][520];    // [row][k]: c_prev
  __shared__ float accS[10][272];              // 10 16x16 tiles, row stride 17
  __shared__ float biasS[10][16];

  const int tid  = threadIdx.x;
  const int lane = tid & 63;
  const int wv   = tid >> 6;     // wave 0..3
  const int l15  = lane & 15;
  const int lq   = lane >> 4;
  const int bid  = blockIdx.x;
  const int rowg = bid & 15;     // all 16 colg WGs of a rowg share one XCD
  const int colg = bid >> 4;
  const int row0 = rowg << 4;    // 16 batch rows
  const int jc0  = colg << 5;    // 32 h-columns

  // ---- persistent weight B-fragments in registers/AGPRs ----
  f16x8 Bg[4][2][8];
  #pragma unroll
  for (int g = 0; g < 4; ++g)
    #pragma unroll
    for (int ct = 0; ct < 2; ++ct) {
      const int n = (g << 9) + jc0 + (ct << 4) + l15;
      #pragma unroll
      for (int t = 0; t < 8; ++t) {
        const int k = ((wv << 3) + t) * 32 + (lq << 3);
        Bg[g][ct][t] = *(const f16x8*)(wtg + (size_t)n * 1024 + k);
      }
    }
  f16x8 Bd[2][4];
  #pragma unroll
  for (int ct = 0; ct < 2; ++ct) {
    const int n = jc0 + (ct << 4) + l15;
    #pragma unroll
    for (int t = 0; t < 4; ++t) {
      const int k = ((wv << 2) + t) * 32 + (lq << 3);
      Bd[ct][t] = *(const f16x8*)(wtd + (size_t)n * 512 + k);
    }
  }

  // ---- biases -> LDS once ----
  if (tid < 160) {
    const int u = tid >> 4, c = tid & 15;
    const float* bp = (u < 2) ? bi : (u < 4) ? bf : (u < 6) ? bog : (u < 8) ? bc : bdec;
    biasS[u][c] = bp[jc0 + ((u & 1) << 4) + c];
  }
  __syncthreads();

  const f16* AgF = &Ag[0][0];
  const f16* AdF = &Ad[0][0];
  const int a_base  = l15 * 1032 + (lq << 3);
  const int ad_base = l15 * 520 + (lq << 3);

  // owner-stationary c state: thread owns (row er, cols 2*eq, 2*eq+1)
  const int er   = tid >> 4;
  const int eq   = tid & 15;
  const int gb_e = row0 + er;
  float c_reg[2] = {0.f, 0.f};

  unsigned* const flg = flg_base + rowg * 16;   // 64B line per rowg
  const int gb0 = row0 + (wv << 2);             // first of this wave's 4 rows

  // ---- preload x(s=0) + tim(s=0) into registers ----
  float4 px0[4], px1[4];
  float t_pf;
  #pragma unroll
  for (int rr = 0; rr < 4; ++rr) {
    const int gb = row0 + (wv << 2) + rr;
    const float4* xr = (const float4*)(x + ((size_t)gb * S_) * D_);
    px0[rr] = xr[lane * 2];
    px1[rr] = xr[lane * 2 + 1];
  }
  t_pf = tim[(size_t)gb_e * S_];

  for (int s = 0; s < S_; ++s) {
    const int cur = s & 1, nxt = cur ^ 1;
    const f16* hcur = h16 + (size_t)cur * (B_ * H_);
    const f16* ccur = c16 + (size_t)cur * (B_ * H_);

    // ---- write prefetched x_s to LDS (cvt fp32->f16) ----
    #pragma unroll
    for (int rr = 0; rr < 4; ++rr) {
      const int r = (wv << 2) + rr;
      f16x8 xv;
      xv[0] = (f16)px0[rr].x; xv[1] = (f16)px0[rr].y;
      xv[2] = (f16)px0[rr].z; xv[3] = (f16)px0[rr].w;
      xv[4] = (f16)px1[rr].x; xv[5] = (f16)px1[rr].y;
      xv[6] = (f16)px1[rr].z; xv[7] = (f16)px1[rr].w;
      *(f16x8*)&Ag[r][lane << 3] = xv;
    }
    // bias-init accumulator tiles
    {
      const int r = tid >> 4, c = tid & 15;
      const int li = r * 17 + c;
      #pragma unroll
      for (int u = 0; u < 10; ++u) accS[u][li] = biasS[u][c];
    }
    const float t_cur = t_pf;

    // ---- prefetch x(s+1) + tim(s+1): whole step to complete ----
    if (s + 1 < S_) {
      #pragma unroll
      for (int rr = 0; rr < 4; ++rr) {
        const int gb = row0 + (wv << 2) + rr;
        const float4* xr = (const float4*)(x + ((size_t)gb * S_ + (s + 1)) * D_);
        px0[rr] = xr[lane * 2];
        px1[rr] = xr[lane * 2 + 1];
      }
      t_pf = tim[(size_t)gb_e * S_ + s + 1];
    }

    // ---- wait for row-group peers: poll 16 epoch flags in parallel ----
    if (s > 0 && wv == 0) {
      const unsigned* fp = flg + l15;
      const unsigned tgt = (unsigned)s;
      while (true) {
        unsigned v;
        asm volatile("global_load_dword %0, %1, off sc0\n\t"
                     "s_waitcnt vmcnt(0)"
                     : "=v"(v) : "v"(fp) : "memory");
        unsigned long long m = __ballot(v >= tgt);
        if ((m & 0xFFFFull) == 0xFFFFull) break;
        __builtin_amdgcn_s_sleep(1);
      }
    }
    __syncthreads();

    // ---- h/c staging: sc0 loads (L1 bypass, L2-served), batched ----
    {
      const f16* hp = hcur + (size_t)gb0 * H_ + (lane << 3);
      const f16* cp = ccur + (size_t)gb0 * H_ + (lane << 3);
      u32x4 h0, h1, h2, h3;
      asm volatile(
        "global_load_dwordx4 %0, %4, off sc0\n\t"
        "global_load_dwordx4 %1, %4, off offset:1024 sc0\n\t"
        "global_load_dwordx4 %2, %4, off offset:2048 sc0\n\t"
        "global_load_dwordx4 %3, %4, off offset:3072 sc0\n\t"
        "s_waitcnt vmcnt(0)"
        : "=&v"(h0), "=&v"(h1), "=&v"(h2), "=&v"(h3)
        : "v"(hp) : "memory");
      const int r = wv << 2;
      *(u32x4*)&Ag[r + 0][512 + (lane << 3)] = h0;
      *(u32x4*)&Ag[r + 1][512 + (lane << 3)] = h1;
      *(u32x4*)&Ag[r + 2][512 + (lane << 3)] = h2;
      *(u32x4*)&Ag[r + 3][512 + (lane << 3)] = h3;
      u32x4 c0, c1, c2, c3;
      asm volatile(
        "global_load_dwordx4 %0, %4, off sc0\n\t"
        "global_load_dwordx4 %1, %4, off offset:1024 sc0\n\t"
        "global_load_dwordx4 %2, %4, off offset:2048 sc0\n\t"
        "global_load_dwordx4 %3, %4, off offset:3072 sc0\n\t"
        "s_waitcnt vmcnt(0)"
        : "=&v"(c0), "=&v"(c1), "=&v"(c2), "=&v"(c3)
        : "v"(cp) : "memory");
      *(u32x4*)&Ad[r + 0][lane << 3] = c0;
      *(u32x4*)&Ad[r + 1][lane << 3] = c1;
      *(u32x4*)&Ad[r + 2][lane << 3] = c2;
      *(u32x4*)&Ad[r + 3][lane << 3] = c3;
    }
    __syncthreads();

    // ---- MFMA: K split across 4 waves ----
    f32x4 acc[10];
    #pragma unroll
    for (int u = 0; u < 10; ++u) acc[u] = (f32x4){0.f, 0.f, 0.f, 0.f};
    #pragma unroll
    for (int t = 0; t < 8; ++t) {
      f16x8 a = *(const f16x8*)(AgF + a_base + ((wv << 3) + t) * 32);
      #pragma unroll
      for (int g = 0; g < 4; ++g)
        #pragma unroll
        for (int ct = 0; ct < 2; ++ct)
          acc[(g << 1) + ct] =
              __builtin_amdgcn_mfma_f32_16x16x32_f16(a, Bg[g][ct][t], acc[(g << 1) + ct], 0, 0, 0);
    }
    #pragma unroll
    for (int t = 0; t < 4; ++t) {
      f16x8 a = *(const f16x8*)(AdF + ad_base + ((wv << 2) + t) * 32);
      acc[8] = __builtin_amdgcn_mfma_f32_16x16x32_f16(a, Bd[0][t], acc[8], 0, 0, 0);
      acc[9] = __builtin_amdgcn_mfma_f32_16x16x32_f16(a, Bd[1][t], acc[9], 0, 0, 0);
    }
    // reduce wave partials; C-frag: row=(lane>>4)*4+i, col=lane&15
    #pragma unroll
    for (int u = 0; u < 10; ++u)
      #pragma unroll
      for (int i = 0; i < 4; ++i)
        atomicAdd(&accS[u][((lq << 2) + i) * 17 + l15], acc[u][i]);
    __syncthreads();

    // ---- elementwise cell update: thread owns (er, 2*eq) and (er, 2*eq+1) ----
    {
      const float T = 1.0f / __logf(t_cur + 2.7183f);   // exact ref constant
      float hv[2];
      #pragma unroll
      for (int j = 0; j < 2; ++j) {
        const int cc = (eq << 1) + j;
        const int ct = cc >> 4, cl = cc & 15;
        const int li = er * 17 + cl;
        const float pi = accS[0 + ct][li];
        const float pf = accS[2 + ct][li];
        const float po = accS[4 + ct][li];
        const float pc = accS[6 + ct][li];
        const float ps = accS[8 + ct][li];
        const float cst  = fast_tanh(ps);
        const float chat = c_reg[j] - cst + T * cst;
        const float cnew = fast_sigmoid(pf) * chat + fast_sigmoid(pi) * fast_tanh(pc);
        const float hnew = fast_sigmoid(po) * fast_tanh(cnew);
        c_reg[j] = cnew;
        hv[j] = hnew;
      }
      // plain stores: land in this XCD's L2 (CDNA L1 is read-only)
      const size_t off = (size_t)gb_e * H_ + jc0 + (eq << 1);
      *(unsigned*)(h16 + (size_t)nxt * (B_ * H_) + off) = pack_f16x2(hv[0], hv[1]);
      *(unsigned*)(c16 + (size_t)nxt * (B_ * H_) + off) = pack_f16x2(c_reg[0], c_reg[1]);
      if (s == S_ - 1) {
        *(float2*)(hf32 + off) = make_float2(hv[0], hv[1]);
      }
    }
    __syncthreads();   // compiler emits s_waitcnt vmcnt(0) before s_barrier:
                       // all waves' h/c stores are in L2 here

    // ---- publish epoch: plain store to our own flag slot ----
    if (tid == 0) {
      unsigned* sp = flg + colg;
      unsigned val = (unsigned)(s + 1);
      asm volatile("global_store_dword %0, %1, off" :: "v"(sp), "v"(val) : "memory");
    }
  }
}

// ---------------------------------------------------------------------------
// Head: out = relu(h_last @ Wo + bo) @ W_softmax + b_softmax   (fp32 exact)
// ---------------------------------------------------------------------------
__global__ void head_kernel(const float* __restrict__ hf32,
                            const float* __restrict__ Wo, const float* __restrict__ bo,
                            const float* __restrict__ Wsm, const float* __restrict__ bsm,
                            float* __restrict__ out)
{
  __shared__ float fcS[4][64];
  const int tid = threadIdx.x;
  const int r = tid >> 6, j = tid & 63;
  const int b = blockIdx.x * 4 + r;
  const float* h = hf32 + (size_t)b * 512;
  float acc = 0.f;
  #pragma unroll 8
  for (int k = 0; k < 512; ++k) acc += h[k] * Wo[k * 64 + j];
  fcS[r][j] = fmaxf(acc + bo[j], 0.f);
  __syncthreads();
  if (tid < 8) {
    const int rr = tid >> 1, o = tid & 1;
    float s = bsm[o];
    #pragma unroll 8
    for (int jj = 0; jj < 64; ++jj) s += fcS[rr][jj] * Wsm[jj * 2 + o];
    out[(size_t)(blockIdx.x * 4 + rr) * 2 + o] = s;
  }
}

// ---------------------------------------------------------------------------
extern "C" void kernel_launch(void* const* d_in, const int* in_sizes, int n_in,
                              void* d_out, int out_size, void* d_ws, size_t ws_size,
                              hipStream_t stream)
{
  if (ws_size < (size_t)WS_END) return;

  const float* x    = (const float*)d_in[0];
  const float* tim  = (const float*)d_in[1];
  const float* Wi   = (const float*)d_in[2];
  const float* Ui   = (const float*)d_in[3];
  const float* bi   = (const float*)d_in[4];
  const float* Wf   = (const float*)d_in[5];
  const float* Uf   = (const float*)d_in[6];
  const float* bf   = (const float*)d_in[7];
  const float* Wog  = (const float*)d_in[8];
  const float* Uog  = (const float*)d_in[9];
  const float* bog  = (const float*)d_in[10];
  const float* Wc   = (const float*)d_in[11];
  const float* Uc   = (const float*)d_in[12];
  const float* bc   = (const float*)d_in[13];
  const float* Wd   = (const float*)d_in[14];
  const float* bd   = (const float*)d_in[15];
  const float* Wo   = (const float*)d_in[16];
  const float* bo   = (const float*)d_in[17];
  const float* Wsm  = (const float*)d_in[18];
  const float* bsm  = (const float*)d_in[19];

  char* ws    = (char*)d_ws;
  f16*  wtg   = (f16*)(ws + WS_WTG);
  f16*  wtd   = (f16*)(ws + WS_WTD);
  f16*  h16   = (f16*)(ws + WS_H16);
  f16*  c16   = (f16*)(ws + WS_C16);
  float* hf32 = (float*)(ws + WS_HF32);
  unsigned* flg = (unsigned*)(ws + WS_FLG);

  // zero h/c buffers + hf32 + flags (ws is poisoned 0xAA before each call)
  (void)hipMemsetAsync(ws + WS_H16, 0, WS_END - WS_H16, stream);

  pack_weights<<<9216, 256, 0, stream>>>(Wi, Ui, Wf, Uf, Wog, Uog, Wc, Uc, Wd, wtg, wtd);
  tlstm_main<<<256, 256, 0, stream>>>(x, tim, bi, bf, bog, bc, bd, wtg, wtd,
                                      h16, c16, hf32, flg);
  head_kernel<<<64, 256, 0, stream>>>(hf32, Wo, bo, Wsm, bsm, (float*)d_out);
}